// Round 17
// baseline (48.344 us; speedup 1.0000x reference)
//
#include <hip/hip_runtime.h>

#define NB 512
#define NATOMS 1024
#define NG 256
#define NL 8
#define NK 128

#define KBT 0.59616123f            // 0.0019872041 * 300
#define ALPHA_C 10.0f
#define LN2 0.6931471805599453f
#define LOG2E 1.4426950408889634f
#define INV2BW2 22.222221f         // 1/(2*0.15^2)
#define SCALE2 (INV2BW2 * LOG2E)   // log2-domain scale (~32.05)
#define LOG_NORM (-1.0170649f)     // log(128) + 3*log(2*pi*BW^2)

typedef _Float16 f16x8 __attribute__((ext_vector_type(8)));
typedef float f32x16 __attribute__((ext_vector_type(16)));

__device__ __forceinline__ float fexp2(float x) { return __builtin_amdgcn_exp2f(x); }
__device__ __forceinline__ float flog2(float x) { return __builtin_amdgcn_logf(x); }

__device__ __forceinline__ float wred_min(float v) {
#pragma unroll
  for (int m = 32; m >= 1; m >>= 1) v = fminf(v, __shfl_xor(v, m, 64));
  return v;
}
__device__ __forceinline__ float wred_sum(float v) {
#pragma unroll
  for (int m = 32; m >= 1; m >>= 1) v += __shfl_xor(v, m, 64);
  return v;
}

// ---------------------------------------------------------------------------
// stage1: grid = 2048 entries x 4 b-quarters (NO worklist, NO fill, NO
// atomics -- r16 lesson: the 3-kernel pipeline carried ~10us fixed cost).
// Dead entries (l >= nl) exit on one scalar load before any barrier.
// Block builds its gl's 8KB A-fragment table in LDS once; two accumulating
// 32x32x16 MFMAs per 32-k tile (verified r13-r16 math, absmax 0.0); lane =
// one b (col=lane&31).  LSE split into TWO passes of 2 k-tiles with acc[2]
// (32 VGPRs instead of 64 -> ~6 blocks/CU instead of 4) merged online;
// partner lane^32 merged with 2 shuffles.  Result plain-stored to
// scaled[gl][b] (coalesced half-wave stores); stage2 does the min-over-l.
// ---------------------------------------------------------------------------
__global__ __launch_bounds__(256) void stage1_kernel(
    const float* __restrict__ positions, const float* __restrict__ kde,
    const float* __restrict__ weight, const float* __restrict__ offs,
    const int* __restrict__ atom_idxs, const int* __restrict__ gsizes,
    float* __restrict__ scaled_out) {
  const int gl = blockIdx.x >> 2;
  const int g = gl >> 3, l = gl & 7;
  int gs = gsizes[g];
  int nl = gs < 1 ? 1 : (gs > NL ? NL : gs);
  if (l >= nl) return;                     // dead entry: uniform early exit

  const int t = threadIdx.x;
  const int lane = t & 63;
  const int wid = t >> 6;
  const int col = lane & 31, h = lane >> 5;
  const int b = ((blockIdx.x & 3) << 7) + (wid << 5) + col;

  __shared__ f16x8 tabL[8][64];            // [kt*2+j][lane], 8 KiB

  // --- position gather issued first (hides under the table build) ---
  const int4 idx = *reinterpret_cast<const int4*>(atom_idxs + (gl << 2));
  const int ids[4] = {idx.x, idx.y, idx.z, idx.w};
  const float* pb = positions + (size_t)b * NATOMS * 3;
  float ax[4], ay[4], az[4];
#pragma unroll
  for (int j = 0; j < 4; ++j) {
    const float3 p = *reinterpret_cast<const float3*>(pb + ids[j] * 3);
    ax[j] = p.x; ay[j] = p.y; az[j] = p.z;
  }

  // --- build fragment table: thread k (0..127) fills 4 f16x8 slots ---
  if (t < NK) {
    const float* mp = kde + ((size_t)gl * NK + t) * 6;
    float mu2 = 0.0f;
    _Float16 ah[6], al[6];
#pragma unroll
    for (int q = 0; q < 6; ++q) {
      float mv = mp[q];
      mu2 += mv * mv;
      float a = (2.0f * SCALE2) * mv;
      _Float16 hh = (_Float16)a;
      ah[q] = hh;
      al[q] = (_Float16)(a - (float)hh);
    }
    float z = -SCALE2 * mu2;
    _Float16 z1 = (_Float16)z;
    _Float16 z2 = (_Float16)(z - (float)z1);
    const _Float16 Z = (_Float16)0.0f;
    const int kt = t >> 5, m = t & 31;
    tabL[kt * 2 + 0][m]      = (f16x8){ah[0],ah[1],ah[2],ah[3],ah[4],ah[5],al[0],al[1]};
    tabL[kt * 2 + 0][m + 32] = (f16x8){al[2],al[3],al[4],al[5],ah[0],ah[1],ah[2],ah[3]};
    tabL[kt * 2 + 1][m]      = (f16x8){ah[4],ah[5],al[0],al[1],al[2],al[3],al[4],al[5]};
    tabL[kt * 2 + 1][m + 32] = (f16x8){z1,  z2,  Z,   Z,   Z,   Z,   Z,   Z   };
  }

  // --- distances + B-fragments (overlaps table build) ---
  const int PI_[6] = {0, 0, 0, 1, 1, 2};
  const int PJ_[6] = {1, 2, 3, 2, 3, 3};
  float d[6]; float x2 = 0.0f;
#pragma unroll
  for (int q = 0; q < 6; ++q) {
    float dx = ax[PI_[q]] - ax[PJ_[q]];
    float dy = ay[PI_[q]] - ay[PJ_[q]];
    float dz = az[PI_[q]] - az[PJ_[q]];
    float dd = dx * dx + dy * dy + dz * dz + 1e-12f;
    d[q] = sqrtf(dd);
    x2 += d[q] * d[q];
  }
  const float c2 = -x2 * SCALE2;           // per-b constant (log2 domain)

  _Float16 xh[6], xl[6];
#pragma unroll
  for (int q = 0; q < 6; ++q) {
    _Float16 hh = (_Float16)d[q];
    xh[q] = hh;
    xl[q] = (_Float16)(d[q] - (float)hh);
  }
  const _Float16 ONE = (_Float16)1.0f, Z = (_Float16)0.0f;
  f16x8 Bf0 = (h == 0)
    ? (f16x8){xh[0],xh[1],xh[2],xh[3],xh[4],xh[5],xh[0],xh[1]}
    : (f16x8){xh[2],xh[3],xh[4],xh[5],xl[0],xl[1],xl[2],xl[3]};
  f16x8 Bf1 = (h == 0)
    ? (f16x8){xl[4],xl[5],xl[0],xl[1],xl[2],xl[3],xl[4],xl[5]}
    : (f16x8){ONE,  ONE,  Z,   Z,   Z,   Z,   Z,   Z   };

  __syncthreads();

  // --- two passes of 2 k-tiles, acc[2] (32 VGPRs), online merge ---
  float mloc = -1e30f, sloc = 0.0f;
#pragma unroll
  for (int pass = 0; pass < 2; ++pass) {
    const f32x16 zz = {0.0f};
    f32x16 a0, a1;
    {
      const int kt = pass * 2;
      f16x8 A0 = tabL[kt * 2 + 0][lane];
      f16x8 A1 = tabL[kt * 2 + 1][lane];
      a0 = __builtin_amdgcn_mfma_f32_32x32x16_f16(
          A1, Bf1, __builtin_amdgcn_mfma_f32_32x32x16_f16(A0, Bf0, zz, 0, 0, 0),
          0, 0, 0);
    }
    {
      const int kt = pass * 2 + 1;
      f16x8 A0 = tabL[kt * 2 + 0][lane];
      f16x8 A1 = tabL[kt * 2 + 1][lane];
      a1 = __builtin_amdgcn_mfma_f32_32x32x16_f16(
          A1, Bf1, __builtin_amdgcn_mfma_f32_32x32x16_f16(A0, Bf0, zz, 0, 0, 0),
          0, 0, 0);
    }
    float m0 = fmaxf(fmaxf(a0[0], a0[1]), fmaxf(a0[2], a0[3]));
    float m1 = fmaxf(fmaxf(a0[4], a0[5]), fmaxf(a0[6], a0[7]));
    float m2 = fmaxf(fmaxf(a0[8], a0[9]), fmaxf(a0[10], a0[11]));
    float m3 = fmaxf(fmaxf(a0[12], a0[13]), fmaxf(a0[14], a0[15]));
    float m4 = fmaxf(fmaxf(a1[0], a1[1]), fmaxf(a1[2], a1[3]));
    float m5 = fmaxf(fmaxf(a1[4], a1[5]), fmaxf(a1[6], a1[7]));
    float m6 = fmaxf(fmaxf(a1[8], a1[9]), fmaxf(a1[10], a1[11]));
    float m7 = fmaxf(fmaxf(a1[12], a1[13]), fmaxf(a1[14], a1[15]));
    float mp = fmaxf(fmaxf(fmaxf(m0, m1), fmaxf(m2, m3)),
                     fmaxf(fmaxf(m4, m5), fmaxf(m6, m7)));
    float s0 = 0.0f, s1 = 0.0f;
#pragma unroll
    for (int i = 0; i < 16; ++i) { s0 += fexp2(a0[i] - mp); s1 += fexp2(a1[i] - mp); }
    float sp = s0 + s1;
    // online merge with running (mloc, sloc)
    float nm = fmaxf(mloc, mp);
    sloc = fmaf(sloc, fexp2(mloc - nm), sp * fexp2(mp - nm));
    mloc = nm;
  }

  // --- partner-lane (^32) merge: 2 shuffles total ---
  float mo = __shfl_xor(mloc, 32, 64);
  float so = __shfl_xor(sloc, 32, 64);
  float M = fmaxf(mloc, mo);
  float S = sloc * fexp2(mloc - M) + so * fexp2(mo - M);

  if (h == 0) {
    float lse2 = c2 + M + flog2(S);        // log2(sum_k exp(v_k))
    float logP = lse2 * LN2 - LOG_NORM;
    float sc = -KBT * logP * weight[gl] + offs[gl];
    scaled_out[(size_t)gl * NB + b] = sc;  // coalesced half-wave store
  }
}

// ---------------------------------------------------------------------------
// stage2: block = b.  Thread t = g: recompute nl(g), min over l of
// scaled[g*8+l][b] (L2-resident), then block LSE over the 256 group-mins.
// ---------------------------------------------------------------------------
__global__ __launch_bounds__(256) void stage2_kernel(
    const float* __restrict__ scaled_in, const int* __restrict__ gsizes,
    float* __restrict__ out) {
  const int b = blockIdx.x;
  const int t = threadIdx.x;
  const int lane = t & 63;
  const int wid = t >> 6;
  int gs = gsizes[t];
  int nl = gs < 1 ? 1 : (gs > NL ? NL : gs);
  float v = 1e30f;
  for (int l = 0; l < nl; ++l)
    v = fminf(v, scaled_in[(size_t)((t << 3) + l) * NB + b]);

  __shared__ float sm[4], ss[4];
  float m = wred_min(v);
  if (lane == 0) sm[wid] = m;
  __syncthreads();
  float M = fminf(fminf(sm[0], sm[1]), fminf(sm[2], sm[3]));
  float e = fexp2(-ALPHA_C * LOG2E * (v - M));
  float s = wred_sum(e);
  if (lane == 0) ss[wid] = s;
  __syncthreads();
  if (t == 0) {
    float S = ss[0] + ss[1] + ss[2] + ss[3];
    out[b] = M - flog2(S) * LN2 / ALPHA_C;
  }
}

extern "C" void kernel_launch(void* const* d_in, const int* in_sizes, int n_in,
                              void* d_out, int out_size, void* d_ws, size_t ws_size,
                              hipStream_t stream) {
  const float* positions = (const float*)d_in[0];
  const float* kde       = (const float*)d_in[1];
  const float* weight    = (const float*)d_in[2];
  const float* offs      = (const float*)d_in[3];
  const int*   atom_idxs = (const int*)d_in[4];
  const int*   gsizes    = (const int*)d_in[5];
  float* out = (float*)d_out;

  float* scaled = (float*)d_ws;            // 2048*512*4B = 4 MiB (no init
                                           // needed: stage2 reads only
                                           // entries stage1 wrote)

  stage1_kernel<<<dim3(NG * NL * 4), dim3(256), 0, stream>>>(
      positions, kde, weight, offs, atom_idxs, gsizes, scaled);
  stage2_kernel<<<dim3(NB), dim3(256), 0, stream>>>(scaled, gsizes, out);
}

// Round 18
// 39.178 us; speedup vs baseline: 1.2340x; 1.2340x over previous
//
#include <hip/hip_runtime.h>

#define NB 512
#define NATOMS 1024
#define NG 256
#define NL 8
#define NK 128

#define KBT 0.59616123f            // 0.0019872041 * 300
#define ALPHA_C 10.0f
#define LN2 0.6931471805599453f
#define LOG2E 1.4426950408889634f
#define INV2BW2 22.222221f         // 1/(2*0.15^2)
#define SCALE2 (INV2BW2 * LOG2E)   // log2-domain scale (~32.05)
#define LOG_NORM (-1.0170649f)     // log(128) + 3*log(2*pi*BW^2)

#define WL_CAP 2048                // max (g,l) pairs = NG*NL

typedef _Float16 f16x8 __attribute__((ext_vector_type(8)));
typedef float f32x16 __attribute__((ext_vector_type(16)));

__device__ __forceinline__ float fexp2(float x) { return __builtin_amdgcn_exp2f(x); }
__device__ __forceinline__ float flog2(float x) { return __builtin_amdgcn_logf(x); }

__device__ __forceinline__ float wred_min(float v) {
#pragma unroll
  for (int m = 32; m >= 1; m >>= 1) v = fminf(v, __shfl_xor(v, m, 64));
  return v;
}
__device__ __forceinline__ float wred_sum(float v) {
#pragma unroll
  for (int m = 32; m >= 1; m >>= 1) v += __shfl_xor(v, m, 64);
  return v;
}

// One block: prefix-sum nl over the 256 groups -> packed worklist of active
// (g,l) pairs.  wl[WL_CAP] = count.  (~2us; no gmin fill needed -- stage1
// plain-stores and stage2 recomputes nl, r17-verified.)
__global__ __launch_bounds__(256) void prep_wl(
    const int* __restrict__ gsizes, int* __restrict__ wl) {
  const int t = threadIdx.x;
  const int lane = t & 63, wid = t >> 6;
  int gs = gsizes[t];
  int nl = gs < 1 ? 1 : (gs > NL ? NL : gs);
  int x = nl;
#pragma unroll
  for (int m = 1; m < 64; m <<= 1) {
    int y = __shfl_up(x, m, 64);
    if (lane >= m) x += y;
  }
  __shared__ int wsum[4];
  if (lane == 63) wsum[wid] = x;
  __syncthreads();
  int off = 0;
  for (int i = 0; i < wid; ++i) off += wsum[i];
  int inc = off + x, exc = inc - nl;
  for (int j = 0; j < nl; ++j) wl[exc + j] = (t << 3) | j;   // entry == gl
  if (t == 255) wl[WL_CAP] = inc;
}

// ---------------------------------------------------------------------------
// stage1: block = one worklist entry (compacted grid; r17 measured the
// uncompacted dispatch at 18% occupancy -- dead-block churn).  The block's
// 4 waves are FULLY INDEPENDENT: each builds the entry's 8KB fragment table
// in its OWN LDS quadrant (within-wave write->read, lgkmcnt only, ZERO
// __syncthreads) and processes its b-quarter as 4 groups of 32 with
// double-buffered position prefetch.  Math = r13/r14-verified (absmax 0.0):
// fp16-split contraction, two accumulating 32x32x16 MFMAs per 32-k tile,
// acc[4] independent chains, LSE = register tree + 2 shuffles (lane^32).
// ---------------------------------------------------------------------------
__global__ __launch_bounds__(256) void stage1_kernel(
    const float* __restrict__ positions, const float* __restrict__ kde,
    const float* __restrict__ weight, const float* __restrict__ offs,
    const int* __restrict__ atom_idxs, const int* __restrict__ wl,
    float* __restrict__ scaled_out) {
  const int count = wl[WL_CAP];
  const int w = blockIdx.x;
  if (w >= count) return;                  // contiguous inactive tail
  const int gl = wl[w];

  const int t = threadIdx.x;
  const int lane = t & 63;
  const int wid = t >> 6;                  // wave = b-quarter, independent
  const int col = lane & 31, h = lane >> 5;

  __shared__ f16x8 tabL[4][8][64];         // 32 KiB; [wid] = wave-private

  const int4 idx = *reinterpret_cast<const int4*>(atom_idxs + (gl << 2));
  const int ids[4] = {idx.x, idx.y, idx.z, idx.w};

  // --- group-0 gather issued first (hides under the table build) ---
  float px[2][4], py[2][4], pz[2][4];
  {
    const int b = (wid << 7) + col;        // gg = 0
    const float* pb = positions + (size_t)b * NATOMS * 3;
#pragma unroll
    for (int j = 0; j < 4; ++j) {
      const float3 p = *reinterpret_cast<const float3*>(pb + ids[j] * 3);
      px[0][j] = p.x; py[0][j] = p.y; pz[0][j] = p.z;
    }
  }

  // --- wave-private table build: lane covers k = lane and k+64 ---
#pragma unroll
  for (int r = 0; r < 2; ++r) {
    const int k = lane + (r << 6);
    const float* mp = kde + ((size_t)gl * NK + k) * 6;
    float mu2 = 0.0f;
    _Float16 ah[6], al[6];
#pragma unroll
    for (int q = 0; q < 6; ++q) {
      float mv = mp[q];
      mu2 += mv * mv;
      float a = (2.0f * SCALE2) * mv;
      _Float16 hh = (_Float16)a;
      ah[q] = hh;
      al[q] = (_Float16)(a - (float)hh);
    }
    float z = -SCALE2 * mu2;
    _Float16 z1 = (_Float16)z;
    _Float16 z2 = (_Float16)(z - (float)z1);
    const _Float16 Z = (_Float16)0.0f;
    const int kt = k >> 5, m = k & 31;
    tabL[wid][kt * 2 + 0][m]      = (f16x8){ah[0],ah[1],ah[2],ah[3],ah[4],ah[5],al[0],al[1]};
    tabL[wid][kt * 2 + 0][m + 32] = (f16x8){al[2],al[3],al[4],al[5],ah[0],ah[1],ah[2],ah[3]};
    tabL[wid][kt * 2 + 1][m]      = (f16x8){ah[4],ah[5],al[0],al[1],al[2],al[3],al[4],al[5]};
    tabL[wid][kt * 2 + 1][m + 32] = (f16x8){z1,  z2,  Z,   Z,   Z,   Z,   Z,   Z   };
  }
  // no barrier: same-wave LDS write->read, compiler inserts lgkmcnt wait

  const float wgt = weight[gl], off = offs[gl];
  const int PI_[6] = {0, 0, 0, 1, 1, 2};
  const int PJ_[6] = {1, 2, 3, 2, 3, 3};
  const _Float16 ONE = (_Float16)1.0f, Z = (_Float16)0.0f;
  const f32x16 zz = {0.0f};

#pragma unroll
  for (int gg = 0; gg < 4; ++gg) {
    const int cur = gg & 1;
    // prefetch next group's positions (overlaps this group's compute)
    if (gg < 3) {
      const int bn = (wid << 7) + ((gg + 1) << 5) + col;
      const float* pb = positions + (size_t)bn * NATOMS * 3;
#pragma unroll
      for (int j = 0; j < 4; ++j) {
        const float3 p = *reinterpret_cast<const float3*>(pb + ids[j] * 3);
        px[cur ^ 1][j] = p.x; py[cur ^ 1][j] = p.y; pz[cur ^ 1][j] = p.z;
      }
    }
    const int b = (wid << 7) + (gg << 5) + col;

    // distances
    float d[6]; float x2 = 0.0f;
#pragma unroll
    for (int q = 0; q < 6; ++q) {
      float dx = px[cur][PI_[q]] - px[cur][PJ_[q]];
      float dy = py[cur][PI_[q]] - py[cur][PJ_[q]];
      float dz = pz[cur][PI_[q]] - pz[cur][PJ_[q]];
      float dd = dx * dx + dy * dy + dz * dz + 1e-12f;
      d[q] = sqrtf(dd);
      x2 += d[q] * d[q];
    }
    const float c2 = -x2 * SCALE2;         // per-b constant (log2 domain)

    // B-fragments: 2-way fp16 split, chunk by lane-half (matches table)
    _Float16 xh[6], xl[6];
#pragma unroll
    for (int q = 0; q < 6; ++q) {
      _Float16 hh = (_Float16)d[q];
      xh[q] = hh;
      xl[q] = (_Float16)(d[q] - (float)hh);
    }
    f16x8 Bf0 = (h == 0)
      ? (f16x8){xh[0],xh[1],xh[2],xh[3],xh[4],xh[5],xh[0],xh[1]}
      : (f16x8){xh[2],xh[3],xh[4],xh[5],xl[0],xl[1],xl[2],xl[3]};
    f16x8 Bf1 = (h == 0)
      ? (f16x8){xl[4],xl[5],xl[0],xl[1],xl[2],xl[3],xl[4],xl[5]}
      : (f16x8){ONE,  ONE,  Z,   Z,   Z,   Z,   Z,   Z   };

    // 4 k-tiles x 2 accumulating MFMAs; A-frags from wave-private LDS
    f32x16 acc[4];
#pragma unroll
    for (int kt = 0; kt < 4; ++kt) {
      f16x8 A0 = tabL[wid][kt * 2 + 0][lane];
      f16x8 A1 = tabL[wid][kt * 2 + 1][lane];
      acc[kt] = __builtin_amdgcn_mfma_f32_32x32x16_f16(
          A1, Bf1, __builtin_amdgcn_mfma_f32_32x32x16_f16(A0, Bf0, zz, 0, 0, 0),
          0, 0, 0);
    }

    // LSE over 128 k: 64 in registers + partner lane (1 shfl each)
    float mkt[4];
#pragma unroll
    for (int kt = 0; kt < 4; ++kt) {
      float m0 = fmaxf(fmaxf(acc[kt][0], acc[kt][1]), fmaxf(acc[kt][2], acc[kt][3]));
      float m1 = fmaxf(fmaxf(acc[kt][4], acc[kt][5]), fmaxf(acc[kt][6], acc[kt][7]));
      float m2 = fmaxf(fmaxf(acc[kt][8], acc[kt][9]), fmaxf(acc[kt][10], acc[kt][11]));
      float m3 = fmaxf(fmaxf(acc[kt][12], acc[kt][13]), fmaxf(acc[kt][14], acc[kt][15]));
      mkt[kt] = fmaxf(fmaxf(m0, m1), fmaxf(m2, m3));
    }
    float mx = fmaxf(fmaxf(mkt[0], mkt[1]), fmaxf(mkt[2], mkt[3]));
    mx = fmaxf(mx, __shfl_xor(mx, 32, 64));

    float s0 = 0.0f, s1 = 0.0f, s2 = 0.0f, s3 = 0.0f;
#pragma unroll
    for (int kt = 0; kt < 4; ++kt) {
      s0 += fexp2(acc[kt][0] - mx)  + fexp2(acc[kt][1] - mx)
          + fexp2(acc[kt][2] - mx)  + fexp2(acc[kt][3] - mx);
      s1 += fexp2(acc[kt][4] - mx)  + fexp2(acc[kt][5] - mx)
          + fexp2(acc[kt][6] - mx)  + fexp2(acc[kt][7] - mx);
      s2 += fexp2(acc[kt][8] - mx)  + fexp2(acc[kt][9] - mx)
          + fexp2(acc[kt][10] - mx) + fexp2(acc[kt][11] - mx);
      s3 += fexp2(acc[kt][12] - mx) + fexp2(acc[kt][13] - mx)
          + fexp2(acc[kt][14] - mx) + fexp2(acc[kt][15] - mx);
    }
    float s = (s0 + s1) + (s2 + s3);
    s += __shfl_xor(s, 32, 64);

    if (h == 0) {
      float lse2 = c2 + mx + flog2(s);     // log2(sum_k exp(v_k))
      float logP = lse2 * LN2 - LOG_NORM;
      float sc = -KBT * logP * wgt + off;
      scaled_out[(size_t)gl * NB + b] = sc;   // coalesced half-wave store
    }
  }
}

// stage2 (r17-verified): block = b, thread t = g; recompute nl(g), min over
// l of scaled[g*8+l][b], then block LSE over the 256 group-mins.
__global__ __launch_bounds__(256) void stage2_kernel(
    const float* __restrict__ scaled_in, const int* __restrict__ gsizes,
    float* __restrict__ out) {
  const int b = blockIdx.x;
  const int t = threadIdx.x;
  const int lane = t & 63;
  const int wid = t >> 6;
  int gs = gsizes[t];
  int nl = gs < 1 ? 1 : (gs > NL ? NL : gs);
  float v = 1e30f;
  for (int l = 0; l < nl; ++l)
    v = fminf(v, scaled_in[(size_t)((t << 3) + l) * NB + b]);

  __shared__ float sm[4], ss[4];
  float m = wred_min(v);
  if (lane == 0) sm[wid] = m;
  __syncthreads();
  float M = fminf(fminf(sm[0], sm[1]), fminf(sm[2], sm[3]));
  float e = fexp2(-ALPHA_C * LOG2E * (v - M));
  float s = wred_sum(e);
  if (lane == 0) ss[wid] = s;
  __syncthreads();
  if (t == 0) {
    float S = ss[0] + ss[1] + ss[2] + ss[3];
    out[b] = M - flog2(S) * LN2 / ALPHA_C;
  }
}

extern "C" void kernel_launch(void* const* d_in, const int* in_sizes, int n_in,
                              void* d_out, int out_size, void* d_ws, size_t ws_size,
                              hipStream_t stream) {
  const float* positions = (const float*)d_in[0];
  const float* kde       = (const float*)d_in[1];
  const float* weight    = (const float*)d_in[2];
  const float* offs      = (const float*)d_in[3];
  const int*   atom_idxs = (const int*)d_in[4];
  const int*   gsizes    = (const int*)d_in[5];
  float* out = (float*)d_out;

  float* scaled = (float*)d_ws;                           // 4 MiB @ 0
  int* wl = (int*)((char*)d_ws + (4 << 20));              // ~8 KiB @ 4 MiB

  prep_wl<<<dim3(1), dim3(256), 0, stream>>>(gsizes, wl);
  stage1_kernel<<<dim3(WL_CAP), dim3(256), 0, stream>>>(
      positions, kde, weight, offs, atom_idxs, wl, scaled);
  stage2_kernel<<<dim3(NB), dim3(256), 0, stream>>>(scaled, gsizes, out);
}

// Round 19
// 38.710 us; speedup vs baseline: 1.2489x; 1.0121x over previous
//
#include <hip/hip_runtime.h>

#define NB 512
#define NATOMS 1024
#define NG 256
#define NL 8
#define NK 128

#define KBT 0.59616123f            // 0.0019872041 * 300
#define ALPHA_C 10.0f
#define LN2 0.6931471805599453f
#define LOG2E 1.4426950408889634f
#define INV2BW2 22.222221f         // 1/(2*0.15^2)
#define SCALE2 (INV2BW2 * LOG2E)   // log2-domain scale (~32.05)
#define LOG_NORM (-1.0170649f)     // log(128) + 3*log(2*pi*BW^2)

#define WL_CAP 2048                // max (g,l) pairs = NG*NL

typedef _Float16 f16x8 __attribute__((ext_vector_type(8)));
typedef float f32x16 __attribute__((ext_vector_type(16)));

__device__ __forceinline__ float fexp2(float x) { return __builtin_amdgcn_exp2f(x); }
__device__ __forceinline__ float flog2(float x) { return __builtin_amdgcn_logf(x); }

__device__ __forceinline__ float wred_min(float v) {
#pragma unroll
  for (int m = 32; m >= 1; m >>= 1) v = fminf(v, __shfl_xor(v, m, 64));
  return v;
}
__device__ __forceinline__ float wred_sum(float v) {
#pragma unroll
  for (int m = 32; m >= 1; m >>= 1) v += __shfl_xor(v, m, 64);
  return v;
}

// One block: prefix-sum nl over the 256 groups -> packed worklist of active
// (g,l) pairs.  wl[WL_CAP] = count.  No key-fill (stage1 plain-stores).
__global__ __launch_bounds__(256) void prep_wl(
    const int* __restrict__ gsizes, int* __restrict__ wl) {
  const int t = threadIdx.x;
  const int lane = t & 63, wid = t >> 6;
  int gs = gsizes[t];
  int nl = gs < 1 ? 1 : (gs > NL ? NL : gs);
  int x = nl;
#pragma unroll
  for (int m = 1; m < 64; m <<= 1) {
    int y = __shfl_up(x, m, 64);
    if (lane >= m) x += y;
  }
  __shared__ int wsum[4];
  if (lane == 63) wsum[wid] = x;
  __syncthreads();
  int off = 0;
  for (int i = 0; i < wid; ++i) off += wsum[i];
  int inc = off + x, exc = inc - nl;
  for (int j = 0; j < nl; ++j) wl[exc + j] = (t << 3) | j;   // entry == gl
  if (t == 255) wl[WL_CAP] = inc;
}

// ---------------------------------------------------------------------------
// stage1 = r14's measured-best structure (35.8us total), minus atomics/fill:
// block = (worklist entry w = bid>>2, b-quarter bid&3); compacted grid with
// contiguous dead tail.  Block builds its gl's 8KB A-fragment table in LDS
// once (threads 0..127); two accumulating 32x32x16 MFMAs per 32-k tile
// (fp16-split contraction, verified absmax 0.0 r10-r18); lane = one b
// (col=lane&31), 64 of its 128 k-values in registers, partner lane^32 the
// rest -> LSE = register tree + exactly 2 shuffles.  Result PLAIN-STORED
// (coalesced); stage2 does the min-over-l (r17-verified).
// ---------------------------------------------------------------------------
__global__ __launch_bounds__(256) void stage1_kernel(
    const float* __restrict__ positions, const float* __restrict__ kde,
    const float* __restrict__ weight, const float* __restrict__ offs,
    const int* __restrict__ atom_idxs, const int* __restrict__ wl,
    float* __restrict__ scaled_out) {
  const int count = wl[WL_CAP];
  const int w = blockIdx.x >> 2;
  if (w >= count) return;                  // contiguous inactive tail
  const int gl = wl[w];

  const int t = threadIdx.x;
  const int lane = t & 63;
  const int col = lane & 31, h = lane >> 5;
  const int b = ((blockIdx.x & 3) << 7) + ((t >> 6) << 5) + col;

  __shared__ f16x8 tabL[8][64];            // [kt*2+j][lane], 8 KiB

  // --- position gather issued first (hides under the table build) ---
  const int4 idx = *reinterpret_cast<const int4*>(atom_idxs + (gl << 2));
  const int ids[4] = {idx.x, idx.y, idx.z, idx.w};
  const float* pb = positions + (size_t)b * NATOMS * 3;
  float ax[4], ay[4], az[4];
#pragma unroll
  for (int j = 0; j < 4; ++j) {
    const float3 p = *reinterpret_cast<const float3*>(pb + ids[j] * 3);
    ax[j] = p.x; ay[j] = p.y; az[j] = p.z;
  }

  // --- build fragment table: thread k (0..127) fills 4 f16x8 slots ---
  if (t < NK) {
    const float* mp = kde + ((size_t)gl * NK + t) * 6;
    float mu2 = 0.0f;
    _Float16 ah[6], al[6];
#pragma unroll
    for (int q = 0; q < 6; ++q) {
      float mv = mp[q];
      mu2 += mv * mv;
      float a = (2.0f * SCALE2) * mv;
      _Float16 hh = (_Float16)a;
      ah[q] = hh;
      al[q] = (_Float16)(a - (float)hh);
    }
    float z = -SCALE2 * mu2;
    _Float16 z1 = (_Float16)z;
    _Float16 z2 = (_Float16)(z - (float)z1);
    const _Float16 Z = (_Float16)0.0f;
    const int kt = t >> 5, m = t & 31;
    tabL[kt * 2 + 0][m]      = (f16x8){ah[0],ah[1],ah[2],ah[3],ah[4],ah[5],al[0],al[1]};
    tabL[kt * 2 + 0][m + 32] = (f16x8){al[2],al[3],al[4],al[5],ah[0],ah[1],ah[2],ah[3]};
    tabL[kt * 2 + 1][m]      = (f16x8){ah[4],ah[5],al[0],al[1],al[2],al[3],al[4],al[5]};
    tabL[kt * 2 + 1][m + 32] = (f16x8){z1,  z2,  Z,   Z,   Z,   Z,   Z,   Z   };
  }

  // --- distances + B-fragments (overlaps table build) ---
  const int PI_[6] = {0, 0, 0, 1, 1, 2};
  const int PJ_[6] = {1, 2, 3, 2, 3, 3};
  float d[6]; float x2 = 0.0f;
#pragma unroll
  for (int q = 0; q < 6; ++q) {
    float dx = ax[PI_[q]] - ax[PJ_[q]];
    float dy = ay[PI_[q]] - ay[PJ_[q]];
    float dz = az[PI_[q]] - az[PJ_[q]];
    float dd = dx * dx + dy * dy + dz * dz + 1e-12f;
    d[q] = sqrtf(dd);
    x2 += d[q] * d[q];
  }
  const float c2 = -x2 * SCALE2;           // per-b constant (log2 domain)

  _Float16 xh[6], xl[6];
#pragma unroll
  for (int q = 0; q < 6; ++q) {
    _Float16 hh = (_Float16)d[q];
    xh[q] = hh;
    xl[q] = (_Float16)(d[q] - (float)hh);
  }
  const _Float16 ONE = (_Float16)1.0f, Z = (_Float16)0.0f;
  f16x8 Bf0 = (h == 0)
    ? (f16x8){xh[0],xh[1],xh[2],xh[3],xh[4],xh[5],xh[0],xh[1]}
    : (f16x8){xh[2],xh[3],xh[4],xh[5],xl[0],xl[1],xl[2],xl[3]};
  f16x8 Bf1 = (h == 0)
    ? (f16x8){xl[4],xl[5],xl[0],xl[1],xl[2],xl[3],xl[4],xl[5]}
    : (f16x8){ONE,  ONE,  Z,   Z,   Z,   Z,   Z,   Z   };

  __syncthreads();

  // --- 4 k-tiles x 2 accumulating MFMAs; A-frags from LDS per tile ---
  const f32x16 zz = {0.0f};
  f32x16 acc[4];
#pragma unroll
  for (int kt = 0; kt < 4; ++kt) {
    f16x8 A0 = tabL[kt * 2 + 0][lane];
    f16x8 A1 = tabL[kt * 2 + 1][lane];
    acc[kt] = __builtin_amdgcn_mfma_f32_32x32x16_f16(
        A1, Bf1, __builtin_amdgcn_mfma_f32_32x32x16_f16(A0, Bf0, zz, 0, 0, 0),
        0, 0, 0);
  }

  // --- LSE over 128 k: 64 in registers + partner lane (1 shfl each) ---
  float mkt[4];
#pragma unroll
  for (int kt = 0; kt < 4; ++kt) {
    float m0 = fmaxf(fmaxf(acc[kt][0], acc[kt][1]), fmaxf(acc[kt][2], acc[kt][3]));
    float m1 = fmaxf(fmaxf(acc[kt][4], acc[kt][5]), fmaxf(acc[kt][6], acc[kt][7]));
    float m2 = fmaxf(fmaxf(acc[kt][8], acc[kt][9]), fmaxf(acc[kt][10], acc[kt][11]));
    float m3 = fmaxf(fmaxf(acc[kt][12], acc[kt][13]), fmaxf(acc[kt][14], acc[kt][15]));
    mkt[kt] = fmaxf(fmaxf(m0, m1), fmaxf(m2, m3));
  }
  float mx = fmaxf(fmaxf(mkt[0], mkt[1]), fmaxf(mkt[2], mkt[3]));
  mx = fmaxf(mx, __shfl_xor(mx, 32, 64));

  float s0 = 0.0f, s1 = 0.0f, s2 = 0.0f, s3 = 0.0f;
#pragma unroll
  for (int kt = 0; kt < 4; ++kt) {
    s0 += fexp2(acc[kt][0] - mx)  + fexp2(acc[kt][1] - mx)
        + fexp2(acc[kt][2] - mx)  + fexp2(acc[kt][3] - mx);
    s1 += fexp2(acc[kt][4] - mx)  + fexp2(acc[kt][5] - mx)
        + fexp2(acc[kt][6] - mx)  + fexp2(acc[kt][7] - mx);
    s2 += fexp2(acc[kt][8] - mx)  + fexp2(acc[kt][9] - mx)
        + fexp2(acc[kt][10] - mx) + fexp2(acc[kt][11] - mx);
    s3 += fexp2(acc[kt][12] - mx) + fexp2(acc[kt][13] - mx)
        + fexp2(acc[kt][14] - mx) + fexp2(acc[kt][15] - mx);
  }
  float s = (s0 + s1) + (s2 + s3);
  s += __shfl_xor(s, 32, 64);

  if (h == 0) {
    float lse2 = c2 + mx + flog2(s);       // log2(sum_k exp(v_k))
    float logP = lse2 * LN2 - LOG_NORM;
    float sc = -KBT * logP * weight[gl] + offs[gl];
    scaled_out[(size_t)gl * NB + b] = sc;  // coalesced half-wave store
  }
}

// stage2 (r17-verified): block = b, thread t = g; recompute nl(g), min over
// l of scaled[g*8+l][b] (L2-resident), then block LSE over the group-mins.
__global__ __launch_bounds__(256) void stage2_kernel(
    const float* __restrict__ scaled_in, const int* __restrict__ gsizes,
    float* __restrict__ out) {
  const int b = blockIdx.x;
  const int t = threadIdx.x;
  const int lane = t & 63;
  const int wid = t >> 6;
  int gs = gsizes[t];
  int nl = gs < 1 ? 1 : (gs > NL ? NL : gs);
  float v = 1e30f;
  for (int l = 0; l < nl; ++l)
    v = fminf(v, scaled_in[(size_t)((t << 3) + l) * NB + b]);

  __shared__ float sm[4], ss[4];
  float m = wred_min(v);
  if (lane == 0) sm[wid] = m;
  __syncthreads();
  float M = fminf(fminf(sm[0], sm[1]), fminf(sm[2], sm[3]));
  float e = fexp2(-ALPHA_C * LOG2E * (v - M));
  float s = wred_sum(e);
  if (lane == 0) ss[wid] = s;
  __syncthreads();
  if (t == 0) {
    float S = ss[0] + ss[1] + ss[2] + ss[3];
    out[b] = M - flog2(S) * LN2 / ALPHA_C;
  }
}

extern "C" void kernel_launch(void* const* d_in, const int* in_sizes, int n_in,
                              void* d_out, int out_size, void* d_ws, size_t ws_size,
                              hipStream_t stream) {
  const float* positions = (const float*)d_in[0];
  const float* kde       = (const float*)d_in[1];
  const float* weight    = (const float*)d_in[2];
  const float* offs      = (const float*)d_in[3];
  const int*   atom_idxs = (const int*)d_in[4];
  const int*   gsizes    = (const int*)d_in[5];
  float* out = (float*)d_out;

  float* scaled = (float*)d_ws;                           // 4 MiB @ 0
  int* wl = (int*)((char*)d_ws + (4 << 20));              // ~8 KiB @ 4 MiB

  prep_wl<<<dim3(1), dim3(256), 0, stream>>>(gsizes, wl);
  stage1_kernel<<<dim3(WL_CAP * 4), dim3(256), 0, stream>>>(
      positions, kde, weight, offs, atom_idxs, wl, scaled);
  stage2_kernel<<<dim3(NB), dim3(256), 0, stream>>>(scaled, gsizes, out);
}